// Round 22
// baseline (59.695 us; speedup 1.0000x reference)
//
#include <hip/hip_runtime.h>
#include <hip/hip_bf16.h>

typedef _Float16 half8 __attribute__((ext_vector_type(8)));
typedef float f32x4 __attribute__((ext_vector_type(4)));
typedef unsigned int u32x4 __attribute__((ext_vector_type(4)));

#define N_U      4096
#define N_L      65536
#define NZ       32
#define NSPLIT   256                  // L splits (grid.x of kA)
#define LSLICE   (N_L / NSPLIT)       // 256 L rows per block -> 16 tiles
#define NT       (LSLICE / 16)        // 16 L-tiles per block
#define UT       16                   // u-tiles per wave (16 MFMA per A-load)
#define BM       1024                 // U rows per kA block (4 waves x 16 x 16)
#define GY       (N_U / BM)           // 4

// workspace layout: only the atomic-max keys
#define OFF_P1   0                            // u32 P1key[N_U] (16 KB)

// Order-preserving float <-> uint key (monotone for all finite floats)
__device__ __forceinline__ unsigned int f2key(float f) {
    unsigned int u = __float_as_uint(f);
    return (u & 0x80000000u) ? ~u : (u | 0x80000000u);
}
__device__ __forceinline__ float key2f(unsigned int k) {
    unsigned int u = (k & 0x80000000u) ? (k & 0x7FFFFFFFu) : ~k;
    return __uint_as_float(u);
}

// ---------------------------------------------------------------------------
// Heavy kernel — R17/R21 hot loop, but self-contained: stages L directly from
// the f32 input (convert + row-norm in the stage pass; Lz is L3-warm across
// replays) and converts its own U fragments from Uz. Removes kPre's launch,
// the inter-kernel gap, and the cold Lf16/Uf16 write->read first-touch that
// the z-scaling experiments measured at ~4 us.
__global__ __launch_bounds__(256)
__attribute__((amdgpu_waves_per_eu(4, 4)))
void kA(const float* __restrict__ Lz,
        const float* __restrict__ Uz,
        unsigned int* __restrict__ P1key) {
    __shared__ __align__(16) unsigned char sm[LSLICE * 64 + LSLICE * 4];
    float* slsq = (float*)(sm + LSLICE * 64);

    const int tid  = threadIdx.x;
    const int lane = tid & 63;
    const int wave = tid >> 6;
    const int g    = lane >> 4;    // k-chunk 0..3 (k = g*8+e, same perm A and B)
    const int lc   = lane & 15;

    const int ubase = blockIdx.y * BM + wave * (UT * 16);
    const int lbase = blockIdx.x * LSLICE;

    // ---- stage: thread t -> L row t. f32 load, f16 convert, -0.5*||l||^2.
    // Fragment-major LDS layout: row r chunk j at (r>>4)*1024 + j*256 +
    // (r&15)*16  ->  a wave's A-read is sm + pt*1024 + lane*16 (conflict-free)
    {
        const f32x4* src = (const f32x4*)(Lz + (size_t)(lbase + tid) * NZ);
        unsigned char* dst = sm + ((tid >> 4) * 1024) + ((tid & 15) * 16);
        float s = 0.f;
#pragma unroll
        for (int j = 0; j < 4; ++j) {
            f32x4 a = src[2 * j], b = src[2 * j + 1];
            s = fmaf(a[0], a[0], s); s = fmaf(a[1], a[1], s);
            s = fmaf(a[2], a[2], s); s = fmaf(a[3], a[3], s);
            s = fmaf(b[0], b[0], s); s = fmaf(b[1], b[1], s);
            s = fmaf(b[2], b[2], s); s = fmaf(b[3], b[3], s);
            *(half8*)(dst + j * 256) =
                (half8){(_Float16)a[0], (_Float16)a[1], (_Float16)a[2], (_Float16)a[3],
                        (_Float16)b[0], (_Float16)b[1], (_Float16)b[2], (_Float16)b[3]};
        }
        slsq[tid] = -0.5f * s;
    }

    // ---- U fragments straight from f32 input (R1-proven conversion path)
    half8 bfrag[UT];
#pragma unroll
    for (int t = 0; t < UT; ++t) {
        const f32x4* p = (const f32x4*)(Uz + (size_t)(ubase + t * 16 + lc) * NZ + g * 8);
        f32x4 a = p[0], b = p[1];
        bfrag[t] = (half8){(_Float16)a[0], (_Float16)a[1], (_Float16)a[2], (_Float16)a[3],
                           (_Float16)b[0], (_Float16)b[1], (_Float16)b[2], (_Float16)b[3]};
    }
    // Pin B-fragments: opaque non-rematerializable defs.
#pragma unroll
    for (int t = 0; t < UT; ++t)
        asm volatile("" : "+v"(bfrag[t]));

    float m[UT];
#pragma unroll
    for (int t = 0; t < UT; ++t) m[t] = -INFINITY;

    __syncthreads();

    const unsigned char* abase = sm + lane * 16;

#pragma unroll 2
    for (int lt = 0; lt < NT; ++lt) {
        const int pt = (lt + wave * 4) & (NT - 1);   // per-wave phase stagger
        half8 a = *(const half8*)(abase + pt * 1024);    // contiguous 1KB/wave
        f32x4 c = *(const f32x4*)(slsq + pt * 16 + g * 4);   // 16-lane broadcast
#pragma unroll
        for (int t = 0; t < UT; ++t) {
            f32x4 x = __builtin_amdgcn_mfma_f32_16x16x32_f16(a, bfrag[t], c, 0, 0, 0);
            asm volatile("" : "+v"(x));   // keep D in arch VGPRs
            float y = fmaxf(fmaxf(x[0], x[1]), x[2]);        // v_max3
            m[t] = fmaxf(fmaxf(y, x[3]), m[t]);              // v_max3
        }
    }

#pragma unroll
    for (int t = 0; t < UT; ++t) {
        float v = m[t];
        v = fmaxf(v, __shfl_xor(v, 16));
        v = fmaxf(v, __shfl_xor(v, 32));
        if (g == 0)
            atomicMax(&P1key[ubase + t * 16 + lc], f2key(v));
    }
}

// ---------------------------------------------------------------------------
// Single-block finisher: ||u||^2 from Uz, dd, global min/max, normalize.
__global__ __launch_bounds__(1024) void kB(const unsigned int* __restrict__ P1key,
                                           const float* __restrict__ Uz,
                                           float* __restrict__ out) {
    const int t    = threadIdx.x;       // 0..1023, each handles 4 u's
    const int lane = t & 63;
    const int wid  = t >> 6;

    u32x4 kv = ((const u32x4*)P1key)[t];

    float dd[4], lmin = INFINITY, lmax = -INFINITY;
#pragma unroll
    for (int j = 0; j < 4; ++j) {
        const int u = t * 4 + j;
        const f32x4* p = (const f32x4*)(Uz + (size_t)u * NZ);
        float s = 0.f;
#pragma unroll
        for (int q = 0; q < 8; ++q) {
            f32x4 v = p[q];
            s = fmaf(v[0], v[0], s); s = fmaf(v[1], v[1], s);
            s = fmaf(v[2], v[2], s); s = fmaf(v[3], v[3], s);
        }
        float M   = key2f(kv[j]);                       // max(u.l - 0.5||l||^2)
        float sq  = fmaxf(fmaf(-2.f, M, s), 0.f);       // min squared distance
        float dens = -0.5f * s - 29.406033062549525f;   // -0.5||u||^2-16log2pi
        dd[j] = expf(dens) * (sqrtf(sq) + 1e-18f);
        lmin = fminf(lmin, dd[j]);
        lmax = fmaxf(lmax, dd[j]);
    }

    __shared__ float smn[16], smx[16];
#pragma unroll
    for (int o = 1; o < 64; o <<= 1) {
        lmin = fminf(lmin, __shfl_xor(lmin, o));
        lmax = fmaxf(lmax, __shfl_xor(lmax, o));
    }
    if (lane == 0) { smn[wid] = lmin; smx[wid] = lmax; }
    __syncthreads();
    if (wid == 0) {
        float a = (lane < 16) ? smn[lane] : INFINITY;
        float b = (lane < 16) ? smx[lane] : -INFINITY;
#pragma unroll
        for (int o = 1; o < 16; o <<= 1) {
            a = fminf(a, __shfl_xor(a, o));
            b = fmaxf(b, __shfl_xor(b, o));
        }
        if (lane == 0) { smn[0] = a; smx[0] = b; }
    }
    __syncthreads();
    float mn = smn[0], mx = smx[0];
    float inv = 1.f / ((mx - mn) + 1e-18f);

    f32x4 o4 = (f32x4){(dd[0] - mn) * inv, (dd[1] - mn) * inv,
                       (dd[2] - mn) * inv, (dd[3] - mn) * inv};
    ((f32x4*)out)[t] = o4;
}

// ---------------------------------------------------------------------------
extern "C" void kernel_launch(void* const* d_in, const int* in_sizes, int n_in,
                              void* d_out, int out_size, void* d_ws, size_t ws_size,
                              hipStream_t stream) {
    const float* Uz = (const float*)d_in[1];
    const float* Lz = (const float*)d_in[2];
    float* out = (float*)d_out;
    unsigned char* ws = (unsigned char*)d_ws;

    unsigned int* P1key = (unsigned int*)(ws + OFF_P1);

    // key 0 == -inf in key space: a plain async memset replaces kPre's init
    hipMemsetAsync(P1key, 0, N_U * sizeof(unsigned int), stream);
    dim3 grid(NSPLIT, GY);   // 256 x 4 = 1024 blocks
    kA<<<grid, 256, 0, stream>>>(Lz, Uz, P1key);
    kB<<<1, 1024, 0, stream>>>(P1key, Uz, out);
}